// Round 17
// baseline (1121.444 us; speedup 1.0000x reference)
//
#include <hip/hip_runtime.h>

#define NTOK  49
#define NWIN  1024
#define SCALE 0.17677669529663687f

// LDS (static, 102.4 KB -> 1 block/CU):
//  xb  @0      : [64][400B] x bf16               -- dead after qkv phase
//  obx @0      : [qt][H][64 lane][16B] = 24576   -- aliases xb, written in attn
//  qb  @25600  : [4 tt][6 h][64 lane][16B] = 24576
//  kb  @50176  : [4 tt][6 h][64 lane][16B] = 24576
//  vt  @74752  : [192 ch][144 B] = 27648
#define SMEM_BYTES 102400

typedef __bf16 bfx8 __attribute__((ext_vector_type(8)));
typedef float  f32x4 __attribute__((ext_vector_type(4)));
typedef unsigned long long ull;
typedef unsigned int uint;

union BF8 { bfx8 v; ull q[2]; };
union BFU { __bf16 h[4]; ull q; };

// native casts -> compiler emits v_cvt_pk_bf16_f32 (RNE)
__device__ __forceinline__ ull pack4(f32x4 a) {
    BFU u;
    u.h[0] = (__bf16)a[0]; u.h[1] = (__bf16)a[1];
    u.h[2] = (__bf16)a[2]; u.h[3] = (__bf16)a[3];
    return u.q;
}
__device__ __forceinline__ unsigned short f2bf(float f) {
    uint u = __builtin_bit_cast(uint, f);
    u += 0x7fffu + ((u >> 16) & 1u);
    return (unsigned short)(u >> 16);
}
__device__ __forceinline__ f32x4 mfma16(bfx8 a, bfx8 b, f32x4 c) {
    return __builtin_amdgcn_mfma_f32_16x16x32_bf16(a, b, c, 0, 0, 0);
}

// W1f[oct 0..35][kk 0..5][lane][8]: lane(g,jn) holds qkv_w[oct*16+jn][kk*32+g*8 ..+8]
// W2p[c2t*6+H][lane][8]: e<4 -> proj_w[c2t*16+jn][H*32+4g+e]; e>=4 -> [.. +16+4g+(e-4)]
// biasN[h][i][j pad 64] f32: j<49 -> rpb[rel[i*49+j]*6+h], else -1e30 (tail mask)
extern "C" __global__ void wattn_prep(const float* __restrict__ qkv_w,
                                      const float* __restrict__ proj_w,
                                      const float* __restrict__ rpb,
                                      const int*   __restrict__ rel,
                                      const float* __restrict__ qkv_b,
                                      unsigned short* __restrict__ W1f,
                                      unsigned short* __restrict__ W2p,
                                      float* __restrict__ qkvbs,
                                      float* __restrict__ biasN)
{
    const int i = blockIdx.x * 256 + threadIdx.x;
    if (i < 110592) {
        const int e = i & 7, l = (i >> 3) & 63, f = i >> 9;
        const int kk = f % 6, oct = f / 6;
        const int R = oct * 16 + (l & 15), C = kk * 32 + (l >> 4) * 8 + e;
        float v = qkv_w[R * 192 + C];
        if (oct < 12) v *= SCALE;
        W1f[i] = f2bf(v);
    }
    if (i < 36864) {
        const int e = i & 7, l = (i >> 3) & 63, f = i >> 9;
        const int c2t = f / 6, H = f % 6;
        const int R = c2t * 16 + (l & 15);
        const int C = H * 32 + (e >> 2) * 16 + (l >> 4) * 4 + (e & 3);
        W2p[i] = f2bf(proj_w[R * 192 + C]);
    }
    if (i < 576) qkvbs[i] = (i < 192) ? qkv_b[i] * SCALE : qkv_b[i];
    if (i < 6 * NTOK * 64) {                 // biasN[h][i][j], j padded to 64
        const int h = i / (NTOK * 64), ii = (i / 64) % NTOK, j = i % 64;
        biasN[i] = (j < NTOK) ? rpb[rel[ii * NTOK + j] * 6 + h] : -1e30f;
    }
}

extern "C" __global__ void __launch_bounds__(512, 2)
wattn_fused(const float* __restrict__ x,
            const float* __restrict__ mask,
            const float* __restrict__ proj_b,
            const unsigned short* __restrict__ W1f,
            const unsigned short* __restrict__ W2p,
            const float* __restrict__ qkvbs,
            const float* __restrict__ biasN,
            float* __restrict__ out)
{
    __shared__ char smem[SMEM_BYTES];
    char* const XB  = smem;
    char* const OBX = smem;
    char* const QBp = smem + 25600;
    char* const KBp = smem + 50176;
    char* const VTp = smem + 74752;

    const int tid  = threadIdx.x;
    const int wave = tid >> 6;
    const int lane = tid & 63;
    const int g    = lane >> 4;
    const int jn   = lane & 15;
    const int qt   = wave & 3;
    const int hh   = wave >> 2;
    const size_t b2 = (size_t)blockIdx.x * 2;

    float4 xr[5];                      // window-1 x prefetch (loaded during proj(w0))

    for (int w = 0; w < 2; ++w) {
        // ---- stage x -> bf16 LDS (w0: from global; w1: from xr regs) ----
#pragma unroll
        for (int u = 0; u < 3; ++u) {  // (re)zero pad rows 49..63 (OBX clobbers them)
            const int i = tid + u * 512;
            if (i < 1500)
                *(uint*)(XB + (49 + i / 100) * 400 + (i % 100) * 4) = 0u;
        }
        if (w == 0) {
            const float4* xw = (const float4*)(x + b2 * 9408);
#pragma unroll
            for (int u = 0; u < 5; ++u) {
                const int i = tid + u * 512;
                if (i < 2352) {
                    float4 v = xw[i];
                    f32x4 vv = {v.x, v.y, v.z, v.w};
                    *(ull*)(XB + (i / 48) * 400 + (i % 48) * 8) = pack4(vv);
                }
            }
        } else {
#pragma unroll
            for (int u = 0; u < 5; ++u) {
                const int i = tid + u * 512;
                if (i < 2352) {
                    f32x4 vv = {xr[u].x, xr[u].y, xr[u].z, xr[u].w};
                    *(ull*)(XB + (i / 48) * 400 + (i % 48) * 8) = pack4(vv);
                }
            }
        }
        __syncthreads();                                          // B1

        // ---- qkv: 16 oct-pairs over 8 waves; one xf stream feeds 2 octs ----
#pragma unroll
        for (int jj = 0; jj < 2; ++jj) {
            const int pr = wave + 8 * jj;            // 0..15
            const int octA = pr * 2;
            bfx8 wfA[6], wfB[6];
#pragma unroll
            for (int kk = 0; kk < 6; ++kk) {
                wfA[kk] = *(const bfx8*)(W1f + ((size_t)(octA * 6 + kk) * 64 + lane) * 8);
                wfB[kk] = *(const bfx8*)(W1f + ((size_t)((octA + 1) * 6 + kk) * 64 + lane) * 8);
            }
            if (pr < 12) {                            // Q (pr<6) or K: swapped mfma(w,x)
                const f32x4 biA = *(const f32x4*)(qkvbs + octA * 16 + 4 * g);
                const f32x4 biB = *(const f32x4*)(qkvbs + (octA + 1) * 16 + 4 * g);
                char* const dst = (pr < 6) ? QBp : KBp;
                const int pp = (pr < 6) ? pr : pr - 6;
#pragma unroll
                for (int tt = 0; tt < 4; ++tt) {
                    f32x4 aA = biA, aB = biB;
#pragma unroll
                    for (int kk = 0; kk < 6; ++kk) {
                        bfx8 xf = *(const bfx8*)(XB + (tt * 16 + jn) * 400 + kk * 64 + g * 16);
                        aA = mfma16(wfA[kk], xf, aA);
                        aB = mfma16(wfB[kk], xf, aB);
                    }
                    BF8 o; o.q[0] = pack4(aA); o.q[1] = pack4(aB);
                    *(bfx8*)(dst + ((tt * 6 + pp) * 64 + lane) * 16) = o.v;
                }
            } else {                                  // V pair: unswapped mfma(x,w)
                const float bvA = qkvbs[octA * 16 + jn];
                const float bvB = qkvbs[(octA + 1) * 16 + jn];
                const int cA = octA - 24;             // 0,2,4,6
#pragma unroll
                for (int tt = 0; tt < 4; ++tt) {
                    f32x4 aA = {bvA, bvA, bvA, bvA};
                    f32x4 aB = {bvB, bvB, bvB, bvB};
#pragma unroll
                    for (int kk = 0; kk < 6; ++kk) {
                        bfx8 xf = *(const bfx8*)(XB + (tt * 16 + jn) * 400 + kk * 64 + g * 16);
                        aA = mfma16(xf, wfA[kk], aA);
                        aB = mfma16(xf, wfB[kk], aB);
                    }
                    const int voff = (tt >> 1) * 64 + g * 16 + (tt & 1) * 8;
                    *(ull*)(VTp + (cA * 16 + jn) * 144 + voff)       = pack4(aA);
                    *(ull*)(VTp + ((cA + 1) * 16 + jn) * 144 + voff) = pack4(aB);
                }
            }
        }
        {   // tail: V octs 32..35; wave w: pair 16+(w>>2), tt=w&3
            const int octA = 32 + (wave >> 2) * 2;
            const int tt = wave & 3;
            bfx8 wfA[6], wfB[6];
#pragma unroll
            for (int kk = 0; kk < 6; ++kk) {
                wfA[kk] = *(const bfx8*)(W1f + ((size_t)(octA * 6 + kk) * 64 + lane) * 8);
                wfB[kk] = *(const bfx8*)(W1f + ((size_t)((octA + 1) * 6 + kk) * 64 + lane) * 8);
            }
            const float bvA = qkvbs[octA * 16 + jn];
            const float bvB = qkvbs[(octA + 1) * 16 + jn];
            f32x4 aA = {bvA, bvA, bvA, bvA};
            f32x4 aB = {bvB, bvB, bvB, bvB};
#pragma unroll
            for (int kk = 0; kk < 6; ++kk) {
                bfx8 xf = *(const bfx8*)(XB + (tt * 16 + jn) * 400 + kk * 64 + g * 16);
                aA = mfma16(xf, wfA[kk], aA);
                aB = mfma16(xf, wfB[kk], aB);
            }
            const int cA = octA - 24;                 // 8,10
            const int voff = (tt >> 1) * 64 + g * 16 + (tt & 1) * 8;
            *(ull*)(VTp + (cA * 16 + jn) * 144 + voff)       = pack4(aA);
            *(ull*)(VTp + ((cA + 1) * 16 + jn) * 144 + voff) = pack4(aB);
        }
        __syncthreads();                                          // B2

        // ---- attention: wave (qt,hh) does 3 heads, 2-deep operand pipeline ----
        const int iq = qt * 16 + jn;
        const int ic = iq < NTOK ? iq : NTOK - 1;
        const float* mw = mask + ((b2 + w) & (NWIN - 1)) * (NTOK * NTOK);
        f32x4 mv4[4];
#pragma unroll
        for (int kt = 0; kt < 3; ++kt) {
            float4 t;
            __builtin_memcpy(&t, mw + ic * NTOK + kt * 16 + 4 * g, 16);
            mv4[kt] = (f32x4){t.x, t.y, t.z, t.w};
        }
        {   // kt=3: only j=48 (g=0,r=0) live; rest masked by bias=-1e30
            const float m48 = mw[ic * NTOK + 48];
            mv4[3] = (f32x4){m48, m48, m48, m48};
        }

        bfx8 qfr = *(const bfx8*)(QBp + ((qt * 6 + hh * 3) * 64 + lane) * 16);
        bfx8 kfc[4];
        f32x4 cic[4];
#pragma unroll
        for (int kt = 0; kt < 4; ++kt) {
            kfc[kt] = *(const bfx8*)(KBp + ((kt * 6 + hh * 3) * 64 + lane) * 16);
            const f32x4 bm4 = *(const f32x4*)(biasN + ((size_t)(hh * 3) * NTOK + ic) * 64 + kt * 16 + 4 * g);
            cic[kt] = bm4 + mv4[kt];
        }

#pragma unroll
        for (int hl = 0; hl < 3; ++hl) {
            const int H = hh * 3 + hl;
            f32x4 p[4];
            __builtin_amdgcn_s_setprio(1);
#pragma unroll
            for (int kt = 0; kt < 4; ++kt)
                p[kt] = mfma16(kfc[kt], qfr, cic[kt]);   // C = bias + mask
            __builtin_amdgcn_s_setprio(0);
            // prefetch next head's operands under this head's softmax chain
            bfx8 qfn, kfn[4];
            f32x4 cin[4];
            if (hl < 2) {
                qfn = *(const bfx8*)(QBp + ((qt * 6 + H + 1) * 64 + lane) * 16);
#pragma unroll
                for (int kt = 0; kt < 4; ++kt) {
                    kfn[kt] = *(const bfx8*)(KBp + ((kt * 6 + H + 1) * 64 + lane) * 16);
                    const f32x4 bm4 = *(const f32x4*)(biasN + ((size_t)(H + 1) * NTOK + ic) * 64 + kt * 16 + 4 * g);
                    cin[kt] = bm4 + mv4[kt];
                }
            }
            float mx = -1e30f;
#pragma unroll
            for (int kt = 0; kt < 4; ++kt)
#pragma unroll
                for (int r = 0; r < 4; ++r) mx = fmaxf(mx, p[kt][r]);
            mx = fmaxf(mx, __shfl_xor(mx, 16));
            mx = fmaxf(mx, __shfl_xor(mx, 32));
            float sum = 0.f;
#pragma unroll
            for (int kt = 0; kt < 4; ++kt)
#pragma unroll
                for (int r = 0; r < 4; ++r) {
                    p[kt][r] = __expf(p[kt][r] - mx);
                    sum += p[kt][r];
                }
            sum += __shfl_xor(sum, 16);
            sum += __shfl_xor(sum, 32);
            const float inv = 1.f / sum;
            BF8 p01, p23;
            p01.q[0] = pack4(p[0]); p01.q[1] = pack4(p[1]);
            p23.q[0] = pack4(p[2]); p23.q[1] = pack4(p[3]);
            __builtin_amdgcn_s_setprio(1);
#pragma unroll
            for (int ct = 0; ct < 2; ++ct) {
                const int row = H * 32 + ct * 16 + jn;
                bfx8 v0 = *(const bfx8*)(VTp + row * 144 + g * 16);
                bfx8 v1 = *(const bfx8*)(VTp + row * 144 + 64 + g * 16);
                f32x4 o = {0.f, 0.f, 0.f, 0.f};
                o = mfma16(v0, p01.v, o);
                o = mfma16(v1, p23.v, o);
                *(ull*)(OBX + ((qt * 6 + H) * 64 + lane) * 16 + ct * 8) = pack4(o * inv);
            }
            __builtin_amdgcn_s_setprio(0);
            if (hl < 2) {
                qfr = qfn;
#pragma unroll
                for (int kt = 0; kt < 4; ++kt) { kfc[kt] = kfn[kt]; cic[kt] = cin[kt]; }
            }
        }
        __syncthreads();                                          // B3

        // ---- issue next-window x loads (fly during proj) ----
        if (w == 0) {
            const float4* xw1 = (const float4*)(x + (b2 + 1) * 9408);
#pragma unroll
            for (int u = 0; u < 5; ++u) {
                const int i = tid + u * 512;
                xr[u] = (i < 2352) ? xw1[i] : (float4){0.f, 0.f, 0.f, 0.f};
            }
        }

        // ---- proj: wave owns token-half qh; O frags cached in regs ----
        const int qh = wave & 1;
        bfx8 obc[2][6];
#pragma unroll
        for (int t2 = 0; t2 < 2; ++t2)
#pragma unroll
            for (int H = 0; H < 6; ++H)
                obc[t2][H] = *(const bfx8*)(OBX + (((qh * 2 + t2) * 6 + H) * 64 + lane) * 16);

        float* outp = out + (b2 + w) * 9408;
#pragma unroll
        for (int t = 0; t < 3; ++t) {
            const int c2t = (wave >> 1) + 4 * t;      // 24 jobs: (c2t, qh) each once
            bfx8 wf2[6];
#pragma unroll
            for (int H = 0; H < 6; ++H)
                wf2[H] = *(const bfx8*)(W2p + ((size_t)(c2t * 6 + H) * 64 + lane) * 8);
            const f32x4 pb = *(const f32x4*)(proj_b + c2t * 16 + 4 * g);
#pragma unroll
            for (int t2 = 0; t2 < 2; ++t2) {
                const int qt2 = qh * 2 + t2;
                f32x4 acc = pb;
#pragma unroll
                for (int H = 0; H < 6; ++H)
                    acc = mfma16(wf2[H], obc[t2][H], acc);
                const int tok = qt2 * 16 + jn;
                if (tok < NTOK)
                    *(f32x4*)(outp + tok * 192 + c2t * 16 + 4 * g) = acc;
            }
        }
        if (w == 0) __syncthreads();                              // B4: OBX dead
    }
}

extern "C" void kernel_launch(void* const* d_in, const int* in_sizes, int n_in,
                              void* d_out, int out_size, void* d_ws, size_t ws_size,
                              hipStream_t stream) {
    const float* x      = (const float*)d_in[0];
    const float* mask   = (const float*)d_in[1];
    const float* qkv_w  = (const float*)d_in[2];
    const float* qkv_b  = (const float*)d_in[3];
    const float* proj_w = (const float*)d_in[4];
    const float* proj_b = (const float*)d_in[5];
    const float* rpb    = (const float*)d_in[6];
    const int*   rel    = (const int*)d_in[7];
    float* outp = (float*)d_out;

    char* ws = (char*)d_ws;
    unsigned short* W1f = (unsigned short*)ws;                     // 221184 B
    unsigned short* W2p = (unsigned short*)(ws + 221184);          //  73728 B
    float* qkvbs        = (float*)(ws + 221184 + 73728);           //   2304 B
    float* biasN        = (float*)(ws + 221184 + 73728 + 2304);    //  75264 B

    wattn_prep<<<432, 256, 0, stream>>>(qkv_w, proj_w, rpb, rel, qkv_b,
                                        W1f, W2p, qkvbs, biasN);
    wattn_fused<<<4096, 512, 0, stream>>>(x, mask, proj_b,
                                          W1f, W2p, qkvbs, biasN, outp);
}

// Round 18
// 416.476 us; speedup vs baseline: 2.6927x; 2.6927x over previous
//
#include <hip/hip_runtime.h>

#define NTOK  49
#define NWIN  1024
#define SCALE 0.17677669529663687f

// LDS (static, 102.4 KB -> 1 block/CU):
//  xb  @0      : [64][400B] x bf16               -- dead after qkv phase
//  obx @0      : [qt][H][64 lane][16B] = 24576   -- aliases xb, written in attn
//  qb  @25600  : [4 tt][6 h][64 lane][16B] = 24576
//  kb  @50176  : [4 tt][6 h][64 lane][16B] = 24576
//  vt  @74752  : [192 ch][144 B] = 27648
#define SMEM_BYTES 102400

typedef __bf16 bfx8 __attribute__((ext_vector_type(8)));
typedef float  f32x4 __attribute__((ext_vector_type(4)));
typedef unsigned long long ull;
typedef unsigned int uint;

union BF8 { bfx8 v; ull q[2]; };
union BFU { __bf16 h[4]; ull q; };

// native casts -> compiler emits v_cvt_pk_bf16_f32 (RNE)
__device__ __forceinline__ ull pack4(f32x4 a) {
    BFU u;
    u.h[0] = (__bf16)a[0]; u.h[1] = (__bf16)a[1];
    u.h[2] = (__bf16)a[2]; u.h[3] = (__bf16)a[3];
    return u.q;
}
__device__ __forceinline__ unsigned short f2bf(float f) {
    uint u = __builtin_bit_cast(uint, f);
    u += 0x7fffu + ((u >> 16) & 1u);
    return (unsigned short)(u >> 16);
}
__device__ __forceinline__ f32x4 mfma16(bfx8 a, bfx8 b, f32x4 c) {
    return __builtin_amdgcn_mfma_f32_16x16x32_bf16(a, b, c, 0, 0, 0);
}

// W1f[oct 0..35][kk 0..5][lane][8]: lane(g,jn) holds qkv_w[oct*16+jn][kk*32+g*8 ..+8]
// W2p[c2t*6+H][lane][8]: e<4 -> proj_w[c2t*16+jn][H*32+4g+e]; e>=4 -> [.. +16+4g+(e-4)]
// biasN[h][i][j pad 64] f32: j<49 -> rpb[rel[i*49+j]*6+h], else -1e30 (tail mask)
extern "C" __global__ void wattn_prep(const float* __restrict__ qkv_w,
                                      const float* __restrict__ proj_w,
                                      const float* __restrict__ rpb,
                                      const int*   __restrict__ rel,
                                      const float* __restrict__ qkv_b,
                                      unsigned short* __restrict__ W1f,
                                      unsigned short* __restrict__ W2p,
                                      float* __restrict__ qkvbs,
                                      float* __restrict__ biasN)
{
    const int i = blockIdx.x * 256 + threadIdx.x;
    if (i < 110592) {
        const int e = i & 7, l = (i >> 3) & 63, f = i >> 9;
        const int kk = f % 6, oct = f / 6;
        const int R = oct * 16 + (l & 15), C = kk * 32 + (l >> 4) * 8 + e;
        float v = qkv_w[R * 192 + C];
        if (oct < 12) v *= SCALE;
        W1f[i] = f2bf(v);
    }
    if (i < 36864) {
        const int e = i & 7, l = (i >> 3) & 63, f = i >> 9;
        const int c2t = f / 6, H = f % 6;
        const int R = c2t * 16 + (l & 15);
        const int C = H * 32 + (e >> 2) * 16 + (l >> 4) * 4 + (e & 3);
        W2p[i] = f2bf(proj_w[R * 192 + C]);
    }
    if (i < 576) qkvbs[i] = (i < 192) ? qkv_b[i] * SCALE : qkv_b[i];
    if (i < 6 * NTOK * 64) {                 // biasN[h][i][j], j padded to 64
        const int h = i / (NTOK * 64), ii = (i / 64) % NTOK, j = i % 64;
        biasN[i] = (j < NTOK) ? rpb[rel[ii * NTOK + j] * 6 + h] : -1e30f;
    }
}

extern "C" __global__ void __launch_bounds__(512, 2)
wattn_fused(const float* __restrict__ x,
            const float* __restrict__ mask,
            const float* __restrict__ proj_b,
            const unsigned short* __restrict__ W1f,
            const unsigned short* __restrict__ W2p,
            const float* __restrict__ qkvbs,
            const float* __restrict__ biasN,
            float* __restrict__ out)
{
    __shared__ char smem[SMEM_BYTES];
    char* const XB  = smem;
    char* const OBX = smem;
    char* const QBp = smem + 25600;
    char* const KBp = smem + 50176;
    char* const VTp = smem + 74752;

    const int tid  = threadIdx.x;
    const int wave = tid >> 6;
    const int lane = tid & 63;
    const int g    = lane >> 4;
    const int jn   = lane & 15;
    const int qt   = wave & 3;
    const int hh   = wave >> 2;
    const size_t b = blockIdx.x;

    // ---- stage x -> bf16 LDS, zero pad rows 49..63 ----
#pragma unroll
    for (int u = 0; u < 3; ++u) {
        const int i = tid + u * 512;
        if (i < 1500)
            *(uint*)(XB + (49 + i / 100) * 400 + (i % 100) * 4) = 0u;
    }
    {
        const float4* xw = (const float4*)(x + b * 9408);
#pragma unroll
        for (int u = 0; u < 5; ++u) {
            const int i = tid + u * 512;
            if (i < 2352) {
                float4 v = xw[i];
                f32x4 vv = {v.x, v.y, v.z, v.w};
                *(ull*)(XB + (i / 48) * 400 + (i % 48) * 8) = pack4(vv);
            }
        }
    }
    __syncthreads();                                              // B1

    // ---- qkv: 16 oct-pairs over 8 waves (2 each); one xf stream feeds 2 octs ----
#pragma unroll
    for (int jj = 0; jj < 2; ++jj) {
        const int pr = wave + 8 * jj;            // 0..15
        const int octA = pr * 2;
        bfx8 wfA[6], wfB[6];
#pragma unroll
        for (int kk = 0; kk < 6; ++kk) {
            wfA[kk] = *(const bfx8*)(W1f + ((size_t)(octA * 6 + kk) * 64 + lane) * 8);
            wfB[kk] = *(const bfx8*)(W1f + ((size_t)((octA + 1) * 6 + kk) * 64 + lane) * 8);
        }
        if (pr < 12) {                            // Q (pr<6) or K: swapped mfma(w,x)
            const f32x4 biA = *(const f32x4*)(qkvbs + octA * 16 + 4 * g);
            const f32x4 biB = *(const f32x4*)(qkvbs + (octA + 1) * 16 + 4 * g);
            char* const dst = (pr < 6) ? QBp : KBp;
            const int pp = (pr < 6) ? pr : pr - 6;
#pragma unroll
            for (int tt = 0; tt < 4; ++tt) {
                f32x4 aA = biA, aB = biB;
#pragma unroll
                for (int kk = 0; kk < 6; ++kk) {
                    bfx8 xf = *(const bfx8*)(XB + (tt * 16 + jn) * 400 + kk * 64 + g * 16);
                    aA = mfma16(wfA[kk], xf, aA);
                    aB = mfma16(wfB[kk], xf, aB);
                }
                BF8 o; o.q[0] = pack4(aA); o.q[1] = pack4(aB);
                *(bfx8*)(dst + ((tt * 6 + pp) * 64 + lane) * 16) = o.v;
            }
        } else {                                  // V pair: unswapped mfma(x,w)
            const float bvA = qkvbs[octA * 16 + jn];
            const float bvB = qkvbs[(octA + 1) * 16 + jn];
            const int cA = octA - 24;             // 0,2,4,6
#pragma unroll
            for (int tt = 0; tt < 4; ++tt) {
                f32x4 aA = {bvA, bvA, bvA, bvA};
                f32x4 aB = {bvB, bvB, bvB, bvB};
#pragma unroll
                for (int kk = 0; kk < 6; ++kk) {
                    bfx8 xf = *(const bfx8*)(XB + (tt * 16 + jn) * 400 + kk * 64 + g * 16);
                    aA = mfma16(xf, wfA[kk], aA);
                    aB = mfma16(xf, wfB[kk], aB);
                }
                const int voff = (tt >> 1) * 64 + g * 16 + (tt & 1) * 8;
                *(ull*)(VTp + (cA * 16 + jn) * 144 + voff)       = pack4(aA);
                *(ull*)(VTp + ((cA + 1) * 16 + jn) * 144 + voff) = pack4(aB);
            }
        }
    }
    {   // tail: V octs 32..35 (pairs 16,17); wave w: pair 16+(w>>2), tt=w&3
        const int octA = 32 + (wave >> 2) * 2;
        const int tt = wave & 3;
        bfx8 wfA[6], wfB[6];
#pragma unroll
        for (int kk = 0; kk < 6; ++kk) {
            wfA[kk] = *(const bfx8*)(W1f + ((size_t)(octA * 6 + kk) * 64 + lane) * 8);
            wfB[kk] = *(const bfx8*)(W1f + ((size_t)((octA + 1) * 6 + kk) * 64 + lane) * 8);
        }
        const float bvA = qkvbs[octA * 16 + jn];
        const float bvB = qkvbs[(octA + 1) * 16 + jn];
        f32x4 aA = {bvA, bvA, bvA, bvA};
        f32x4 aB = {bvB, bvB, bvB, bvB};
#pragma unroll
        for (int kk = 0; kk < 6; ++kk) {
            bfx8 xf = *(const bfx8*)(XB + (tt * 16 + jn) * 400 + kk * 64 + g * 16);
            aA = mfma16(xf, wfA[kk], aA);
            aB = mfma16(xf, wfB[kk], aB);
        }
        const int cA = octA - 24;                 // 8,10
        const int voff = (tt >> 1) * 64 + g * 16 + (tt & 1) * 8;
        *(ull*)(VTp + (cA * 16 + jn) * 144 + voff)       = pack4(aA);
        *(ull*)(VTp + ((cA + 1) * 16 + jn) * 144 + voff) = pack4(aB);
    }

    // ---- mask loads hoisted above B2: L2 latency hides under barrier drain ----
    const int iq = qt * 16 + jn;
    const int ic = iq < NTOK ? iq : NTOK - 1;
    const float* mw = mask + (b & (NWIN - 1)) * (NTOK * NTOK);
    f32x4 mv4[4];
#pragma unroll
    for (int kt = 0; kt < 3; ++kt) {              // cols kt*16+4g .. +3 (<49): in-row
        float4 t;
        __builtin_memcpy(&t, mw + ic * NTOK + kt * 16 + 4 * g, 16);
        mv4[kt] = (f32x4){t.x, t.y, t.z, t.w};
    }
    {   // kt=3: only j=48 (g=0,r=0) is live; rest masked by bias=-1e30
        const float m48 = mw[ic * NTOK + 48];
        mv4[3] = (f32x4){m48, m48, m48, m48};
    }
    __syncthreads();                                              // B2

    // ---- attention: wave (qt,hh) does 3 heads, 2-deep operand pipeline ----
    // head-0 operands
    bfx8 qfr = *(const bfx8*)(QBp + ((qt * 6 + hh * 3) * 64 + lane) * 16);
    bfx8 kfc[4];
    f32x4 cic[4];
#pragma unroll
    for (int kt = 0; kt < 4; ++kt) {
        kfc[kt] = *(const bfx8*)(KBp + ((kt * 6 + hh * 3) * 64 + lane) * 16);
        const f32x4 bm4 = *(const f32x4*)(biasN + ((size_t)(hh * 3) * NTOK + ic) * 64 + kt * 16 + 4 * g);
        cic[kt] = bm4 + mv4[kt];
    }

#pragma unroll
    for (int hl = 0; hl < 3; ++hl) {
        const int H = hh * 3 + hl;
        f32x4 p[4];
        __builtin_amdgcn_s_setprio(1);
#pragma unroll
        for (int kt = 0; kt < 4; ++kt)
            p[kt] = mfma16(kfc[kt], qfr, cic[kt]);   // C = bias + mask
        __builtin_amdgcn_s_setprio(0);
        // prefetch next head's operands under this head's softmax chain
        bfx8 qfn, kfn[4];
        f32x4 cin[4];
        if (hl < 2) {
            qfn = *(const bfx8*)(QBp + ((qt * 6 + H + 1) * 64 + lane) * 16);
#pragma unroll
            for (int kt = 0; kt < 4; ++kt) {
                kfn[kt] = *(const bfx8*)(KBp + ((kt * 6 + H + 1) * 64 + lane) * 16);
                const f32x4 bm4 = *(const f32x4*)(biasN + ((size_t)(H + 1) * NTOK + ic) * 64 + kt * 16 + 4 * g);
                cin[kt] = bm4 + mv4[kt];
            }
        }
        float mx = -1e30f;
#pragma unroll
        for (int kt = 0; kt < 4; ++kt)
#pragma unroll
            for (int r = 0; r < 4; ++r) mx = fmaxf(mx, p[kt][r]);
        mx = fmaxf(mx, __shfl_xor(mx, 16));
        mx = fmaxf(mx, __shfl_xor(mx, 32));
        float sum = 0.f;
#pragma unroll
        for (int kt = 0; kt < 4; ++kt)
#pragma unroll
            for (int r = 0; r < 4; ++r) {
                p[kt][r] = __expf(p[kt][r] - mx);
                sum += p[kt][r];
            }
        sum += __shfl_xor(sum, 16);
        sum += __shfl_xor(sum, 32);
        const float inv = 1.f / sum;
        BF8 p01, p23;
        p01.q[0] = pack4(p[0]); p01.q[1] = pack4(p[1]);
        p23.q[0] = pack4(p[2]); p23.q[1] = pack4(p[3]);
        __builtin_amdgcn_s_setprio(1);
#pragma unroll
        for (int ct = 0; ct < 2; ++ct) {
            const int row = H * 32 + ct * 16 + jn;
            bfx8 v0 = *(const bfx8*)(VTp + row * 144 + g * 16);
            bfx8 v1 = *(const bfx8*)(VTp + row * 144 + 64 + g * 16);
            f32x4 o = {0.f, 0.f, 0.f, 0.f};
            o = mfma16(v0, p01.v, o);
            o = mfma16(v1, p23.v, o);
            *(ull*)(OBX + ((qt * 6 + H) * 64 + lane) * 16 + ct * 8) = pack4(o * inv);
        }
        __builtin_amdgcn_s_setprio(0);
        if (hl < 2) {
            qfr = qfn;
#pragma unroll
            for (int kt = 0; kt < 4; ++kt) { kfc[kt] = kfn[kt]; cic[kt] = cin[kt]; }
        }
    }
    __syncthreads();                                              // B3

    // ---- proj: wave owns token-half qh; O frags cached in regs (12 b128) ----
    const int qh = wave & 1;
    bfx8 obc[2][6];
#pragma unroll
    for (int t2 = 0; t2 < 2; ++t2)
#pragma unroll
        for (int H = 0; H < 6; ++H)
            obc[t2][H] = *(const bfx8*)(OBX + (((qh * 2 + t2) * 6 + H) * 64 + lane) * 16);

    float* outp = out + b * 9408;
#pragma unroll
    for (int t = 0; t < 3; ++t) {
        const int c2t = (wave >> 1) + 4 * t;      // 24 jobs: (c2t, qh) each once
        bfx8 wf2[6];
#pragma unroll
        for (int H = 0; H < 6; ++H)
            wf2[H] = *(const bfx8*)(W2p + ((size_t)(c2t * 6 + H) * 64 + lane) * 8);
        const f32x4 pb = *(const f32x4*)(proj_b + c2t * 16 + 4 * g);
#pragma unroll
        for (int t2 = 0; t2 < 2; ++t2) {
            const int qt2 = qh * 2 + t2;
            f32x4 acc = pb;
#pragma unroll
            for (int H = 0; H < 6; ++H)
                acc = mfma16(wf2[H], obc[t2][H], acc);
            const int tok = qt2 * 16 + jn;
            if (tok < NTOK)
                *(f32x4*)(outp + tok * 192 + c2t * 16 + 4 * g) = acc;
        }
    }
}

extern "C" void kernel_launch(void* const* d_in, const int* in_sizes, int n_in,
                              void* d_out, int out_size, void* d_ws, size_t ws_size,
                              hipStream_t stream) {
    const float* x      = (const float*)d_in[0];
    const float* mask   = (const float*)d_in[1];
    const float* qkv_w  = (const float*)d_in[2];
    const float* qkv_b  = (const float*)d_in[3];
    const float* proj_w = (const float*)d_in[4];
    const float* proj_b = (const float*)d_in[5];
    const float* rpb    = (const float*)d_in[6];
    const int*   rel    = (const int*)d_in[7];
    float* outp = (float*)d_out;

    char* ws = (char*)d_ws;
    unsigned short* W1f = (unsigned short*)ws;                     // 221184 B
    unsigned short* W2p = (unsigned short*)(ws + 221184);          //  73728 B
    float* qkvbs        = (float*)(ws + 221184 + 73728);           //   2304 B
    float* biasN        = (float*)(ws + 221184 + 73728 + 2304);    //  75264 B

    wattn_prep<<<432, 256, 0, stream>>>(qkv_w, proj_w, rpb, rel, qkv_b,
                                        W1f, W2p, qkvbs, biasN);
    wattn_fused<<<8192, 512, 0, stream>>>(x, mask, proj_b,
                                          W1f, W2p, qkvbs, biasN, outp);
}